// Round 13
// baseline (4084.705 us; speedup 1.0000x reference)
//
#include <hip/hip_runtime.h>

// DAA autoencoder — R10 champion structure + unroll-4 k-loop, DIAGNOSTIC
// build: k-loop wrapped in an idempotent REP loop (re-min of identical
// values is bit-identical) to inflate daa dispatches above the ~40us
// harness-fill floor so rocprof top-5 finally shows their counters.
//   layer0: h[b][o]   = min_i ( sel0[o][i] ? x[b][i] : 2.0f )
//   layer1: out[b][o] = max_i ( sel1[o][i] ? h[b][i] : -1.0f )
// B=256, IN=1024, HID=512.
//
// Bit-exactness: addend = sel ? 0.0f : +/-inf; x + 0.0f == x exactly;
// +/-inf never wins min/max vs finite; acc init = off (2.0/-1.0)
// reproduces the all-deselected row exactly. REP re-applies the same
// min/max -> idempotent, deterministic.

#define NB 256   // batch

// ---- pack: transpose x AND expand the scalar-path half of sel ------------
__global__ __launch_bounds__(256) void pack_all(
    const float* __restrict__ x,    float4* __restrict__ xT4,   // [256][256]
    const int*   __restrict__ sel0, float4* __restrict__ a0h,   // [256][256]
    const int*   __restrict__ sel1, float4* __restrict__ a1h)   // [512][128]
{
    const int t = blockIdx.x * 256 + threadIdx.x;   // 65536 threads
    const float pinf = __builtin_inff();

    {   // a0h: rows j=(ot*4+r) <- sel0 row ot*8+4+r
        const int j = t >> 8, i4 = t & 255;
        const int srow = (j >> 2) * 8 + 4 + (j & 3);
        const int4 v = ((const int4*)sel0)[srow * 256 + i4];
        a0h[t] = make_float4(v.x ? 0.f : pinf, v.y ? 0.f : pinf,
                             v.z ? 0.f : pinf, v.w ? 0.f : pinf);
    }
    {   // a1h
        const int j = t >> 7, i4 = t & 127;
        const int srow = (j >> 2) * 8 + 4 + (j & 3);
        const int4 v = ((const int4*)sel1)[srow * 128 + i4];
        a1h[t] = make_float4(v.x ? 0.f : -pinf, v.y ? 0.f : -pinf,
                             v.z ? 0.f : -pinf, v.w ? 0.f : -pinf);
    }

    if (blockIdx.x < 64) {      // x transpose
        __shared__ float tt[64][65];
        const int bx = blockIdx.x % 16, by = blockIdx.x / 16;
        const int i0 = bx * 64, b0 = by * 64;
        const int li = threadIdx.x & 63, lb = threadIdx.x >> 6;
#pragma unroll
        for (int r = 0; r < 64; r += 4)
            tt[lb + r][li] = x[(size_t)(b0 + lb + r) * 1024 + i0 + li];
        __syncthreads();
        const int sb = threadIdx.x & 63, si = threadIdx.x >> 6;
#pragma unroll
        for (int p = 0; p < 16; p += 4) {
            const int i4 = si + p;
            float4 v = make_float4(tt[sb][4 * i4 + 0], tt[sb][4 * i4 + 1],
                                   tt[sb][4 * i4 + 2], tt[sb][4 * i4 + 3]);
            xT4[(size_t)(i0 / 4 + i4) * NB + b0 + sb] = v;
        }
    }
}

// ---- masked min/max layer: OT=8, unroll-4 k-loop, REP diagnostic loop ----
template<int INF, int S, int MW, int REP, bool ISMIN, bool TOUT>
__global__ __launch_bounds__(64 * S, MW) void daa_layer(
    const float4* __restrict__ inT4,   // [INF/4][NB]
    const int*    __restrict__ sel,    // [OUTF][INF] (rows o0..o0+3 -> LDS)
    const float4* __restrict__ agh,    // pre-expanded rows (o&7)>=4
    float* __restrict__ out, int OUTF)
{
    constexpr int C4 = INF / 4 / S;    // float4 k-steps per wave
    constexpr int R4 = INF / 4;        // float4s per addend row
    const int tid  = threadIdx.x;
    const int lane = tid & 63;
    const int s    = __builtin_amdgcn_readfirstlane(tid >> 6);
    const int bch  = blockIdx.x & 3;
    const int o0   = (blockIdx.x >> 2) * 8;
    const int b    = bch * 64 + lane;
    const float off = ISMIN ? 2.0f : -1.0f;
    const float inf = ISMIN ? __builtin_inff() : -__builtin_inff();

    // 32 KB LDS, time-shared: addend rows 0..3 during k-loop, then red[].
    __shared__ float4 uni[2048];
    if (tid < 4 * R4) {
        const int4 v = ((const int4*)sel)[(size_t)o0 * R4 + tid];
        uni[tid] = make_float4(v.x ? 0.f : inf, v.y ? 0.f : inf,
                               v.z ? 0.f : inf, v.w ? 0.f : inf);
    }
    __syncthreads();

    float acc[8];
#pragma unroll
    for (int u = 0; u < 8; ++u) acc[u] = off;

    const float4* __restrict__ xp = inT4 + (size_t)(s * C4) * NB + b;
    const float4* __restrict__ aL = uni + s * C4;
    const float4* __restrict__ aG = agh + ((size_t)(o0 >> 3) * 4) * R4 + s * C4;

#define MM(A, X, AV)                                                   \
    do {                                                               \
        if (ISMIN) {                                                   \
            A = fminf(fminf(A, (X).x + (AV).x), (X).y + (AV).y);       \
            A = fminf(fminf(A, (X).z + (AV).z), (X).w + (AV).w);       \
        } else {                                                       \
            A = fmaxf(fmaxf(A, (X).x + (AV).x), (X).y + (AV).y);       \
            A = fmaxf(fmaxf(A, (X).z + (AV).z), (X).w + (AV).w);       \
        }                                                              \
    } while (0)

    // REP x identical k-loop passes: acc = min(acc, same) — bit-idempotent.
    for (int rep = 0; rep < REP; ++rep) {
#pragma unroll
        for (int cc = 0; cc < C4; cc += 4) {
            // 4 x-loads issued together (ILP-4); ds/s_load offsets are
            // compile-time immediates after full unroll.
            const float4 x0 = xp[(size_t)(cc + 0) * NB];
            const float4 x1 = xp[(size_t)(cc + 1) * NB];
            const float4 x2 = xp[(size_t)(cc + 2) * NB];
            const float4 x3 = xp[(size_t)(cc + 3) * NB];
#pragma unroll
            for (int u = 0; u < 4; ++u) {
                MM(acc[u], x0, aL[u * R4 + cc + 0]);
                MM(acc[u], x1, aL[u * R4 + cc + 1]);
                MM(acc[u], x2, aL[u * R4 + cc + 2]);
                MM(acc[u], x3, aL[u * R4 + cc + 3]);
            }
#pragma unroll
            for (int u = 0; u < 4; ++u) {
                MM(acc[4 + u], x0, aG[u * R4 + cc + 0]);
                MM(acc[4 + u], x1, aG[u * R4 + cc + 1]);
                MM(acc[4 + u], x2, aG[u * R4 + cc + 2]);
                MM(acc[4 + u], x3, aG[u * R4 + cc + 3]);
            }
        }
    }
#undef MM

    __syncthreads();
    float* redf = (float*)uni;          // red[16][8][64]
#pragma unroll
    for (int u = 0; u < 8; ++u) redf[(s * 8 + u) * 64 + lane] = acc[u];
    __syncthreads();

    if (tid < 512) {
        const int u = tid >> 6, ln = tid & 63;
        float v = redf[u * 64 + ln];
#pragma unroll
        for (int ss = 1; ss < S; ++ss) {
            const float q = redf[(ss * 8 + u) * 64 + ln];
            v = ISMIN ? fminf(v, q) : fmaxf(v, q);
        }
        redf[u * 64 + ln] = v;
    }
    __syncthreads();

    if (tid < 64) {
        const int bb = bch * 64 + tid;
        const float4 lo = make_float4(redf[0 * 64 + tid], redf[1 * 64 + tid],
                                      redf[2 * 64 + tid], redf[3 * 64 + tid]);
        const float4 hi = make_float4(redf[4 * 64 + tid], redf[5 * 64 + tid],
                                      redf[6 * 64 + tid], redf[7 * 64 + tid]);
        if (TOUT) {
            ((float4*)out)[(size_t)(o0 >> 2) * NB + bb]       = lo;
            ((float4*)out)[((size_t)(o0 >> 2) + 1) * NB + bb] = hi;
        } else {
            float4* p = (float4*)(out + (size_t)bb * OUTF + o0);
            p[0] = lo; p[1] = hi;
        }
    }
}

extern "C" void kernel_launch(void* const* d_in, const int* in_sizes, int n_in,
                              void* d_out, int out_size, void* d_ws, size_t ws_size,
                              hipStream_t stream) {
    const float* x    = (const float*)d_in[0];  // [256,1024] f32
    const int*   sel0 = (const int*)d_in[1];    // [512,1024] i32
    const int*   sel1 = (const int*)d_in[2];    // [1024,512] i32
    float* out = (float*)d_out;                 // [256,1024] f32

    char* ws = (char*)d_ws;
    float4* xT4 = (float4*)ws;                          // 1 MB
    float*  hT  = (float*)(ws + (1 << 20));             // 0.5 MB
    float4* a0h = (float4*)(ws + 3 * (1 << 19));        // 1 MB
    float4* a1h = (float4*)(ws + 5 * (1 << 19));        // 1 MB

    pack_all<<<256, 256, 0, stream>>>(x, xT4, sel0, a0h, sel1, a1h);
    // DIAGNOSTIC: REP=16 / REP=32 inflate the k-loop so both dispatches
    // exceed the ~40us fill floor and surface in rocprof top-5.
    daa_layer<1024, 16, 4, 16, true,  true ><<<256, 1024, 0, stream>>>(
        xT4, sel0, a0h, hT, 512);
    daa_layer< 512, 16, 8, 32, false, false><<<512, 1024, 0, stream>>>(
        (const float4*)hT, sel1, a1h, out, 1024);
}

// Round 15
// 27.302 us; speedup vs baseline: 149.6113x; 149.6113x over previous
//
#include <hip/hip_runtime.h>
#include <hip/hip_fp16.h>

// DAA autoencoder — fp16 + sequential-slab (R15 = R14 with asm packed math).
//   layer0: h[b][o]   = min_i ( sel0[o][i] ? x[b][i] : 2.0f )
//   layer1: out[b][o] = max_i ( sel1[o][i] ? h[b][i] : -1.0f )
// B=256, IN=1024, HID=512.
//
// R13 diagnostic: k-loop is pure memory streaming (VALUBusy 2.5%, occ 97%,
// 6x L2 fetch amplification on strided columns). Levers: fp16 halves bytes
// and packs 2 edges/VALU-op; slab-major layout makes every wave k-step a
// 1 KB contiguous read. R14 lesson: __hmin2/__hmax2 absent in this ROCm ->
// emit v_pk_{add,min,max}_f16 via inline asm (VOP3P, present on gfx950).
//
// Accuracy: f32->f16 RN error <= 2^-12 = 2.44e-4 on [0,1); min/max are
// 1-Lipschitz selections (no accumulation); +/-inf addends exact; 2.0/-1.0
// exact in f16 => absmax <= 2.44e-4 < threshold 4.10e-4.

#define H_PINF 0x7C00u
#define H_NINF 0xFC00u

__device__ __forceinline__ unsigned pk_add(unsigned a, unsigned b) {
    unsigned r;
    asm("v_pk_add_f16 %0, %1, %2" : "=v"(r) : "v"(a), "v"(b));
    return r;
}
__device__ __forceinline__ unsigned pk_min(unsigned a, unsigned b) {
    unsigned r;
    asm("v_pk_min_f16 %0, %1, %2" : "=v"(r) : "v"(a), "v"(b));
    return r;
}
__device__ __forceinline__ unsigned pk_max(unsigned a, unsigned b) {
    unsigned r;
    asm("v_pk_max_f16 %0, %1, %2" : "=v"(r) : "v"(a), "v"(b));
    return r;
}

__device__ __forceinline__ unsigned hpk(float a, float b) {
    return (unsigned)__half_as_ushort(__float2half(a))
         | ((unsigned)__half_as_ushort(__float2half(b)) << 16);
}
__device__ __forceinline__ float h2f(unsigned short u) {
    __half h = *reinterpret_cast<__half*>(&u);
    return __half2float(h);
}

// ---- K1: expand sel -> fp16 addends; transpose x -> fp16 slabs -----------
__global__ __launch_bounds__(256) void pack_all(
    const float* __restrict__ x,
    const int* __restrict__ sel0, const int* __restrict__ sel1,
    uint4* __restrict__ xH,      // 4 slabs x [128 ioct][64 b] uint4 (fp16)
    uint2* __restrict__ a0f,     // [512][1024] fp16 addends
    uint2* __restrict__ a1f)     // [1024][512] fp16 addends
{
    const int t = blockIdx.x * 256 + threadIdx.x;   // 0..131071
    {   // addend expansion: 1 int4 -> 4 halves (uint2) each, both arrays
        const int4 v = ((const int4*)sel0)[t];
        a0f[t] = make_uint2(
            (v.x ? 0u : H_PINF) | ((v.y ? 0u : H_PINF) << 16),
            (v.z ? 0u : H_PINF) | ((v.w ? 0u : H_PINF) << 16));
        const int4 w = ((const int4*)sel1)[t];
        a1f[t] = make_uint2(
            (w.x ? 0u : H_NINF) | ((w.y ? 0u : H_NINF) << 16),
            (w.z ? 0u : H_NINF) | ((w.w ? 0u : H_NINF) << 16));
    }
    if (blockIdx.x < 64) {      // x transpose+convert: tiles of 64b x 64i
        __shared__ float tt[64][65];
        const int bx = blockIdx.x % 16;   // i-tile
        const int by = blockIdx.x / 16;   // b-slab (bch)
        const int i0 = bx * 64, b0 = by * 64;
        const int li = threadIdx.x & 63, lb = threadIdx.x >> 6;
#pragma unroll
        for (int r = 0; r < 64; r += 4)
            tt[lb + r][li] = x[(size_t)(b0 + lb + r) * 1024 + i0 + li];
        __syncthreads();
#pragma unroll
        for (int k = 0; k < 2; ++k) {
            const int idx = threadIdx.x * 2 + k;    // 512 uint4 per tile
            const int r = idx >> 6, bc = idx & 63;  // local ioct, b-col
            const float* row = &tt[bc][r * 8];
            uint4 wv;
            wv.x = hpk(row[0], row[1]);
            wv.y = hpk(row[2], row[3]);
            wv.z = hpk(row[4], row[5]);
            wv.w = hpk(row[6], row[7]);
            // sequential slab write: 64 consecutive uint4 per (tile, r)
            xH[(size_t)by * 8192 + (size_t)(bx * 8 + r) * 64 + bc] = wv;
        }
    }
}

// ---- masked min/max layer over fp16 slabs --------------------------------
template<int INF, int OT, bool ISMIN, bool TOUT>
__global__ __launch_bounds__(1024, 4) void daa_layer(
    const uint4* __restrict__ xS,     // fp16 slabs [4][INF/8][64]
    const unsigned short* __restrict__ af,  // [OUTF][INF] fp16 addends
    void* __restrict__ outp)
{
    constexpr int S  = 16;            // i-split wave groups
    constexpr int C8 = INF / 8 / S;   // uint4 (8-half) k-steps per wave
    constexpr int RU = INF / 8;       // uint4 per addend/slab row
    const int tid  = threadIdx.x;
    const int lane = tid & 63;
    const int s    = __builtin_amdgcn_readfirstlane(tid >> 6);
    const int bch  = blockIdx.x & 3;
    const int o0   = (blockIdx.x >> 2) * OT;

    // 32 KB LDS, time-shared: fp16 addend rows -> red[S][OT][64] halves
    __shared__ uint4 buf[2048];
    if (tid < (OT / 2) * RU)
        buf[tid] = ((const uint4*)af)[(size_t)o0 * RU + tid];
    __syncthreads();

    union V4 { uint4 u; unsigned w[4]; };

    unsigned acc[OT];
    const unsigned offp = ISMIN ? hpk(2.0f, 2.0f) : hpk(-1.0f, -1.0f);
#pragma unroll
    for (int u = 0; u < OT; ++u) acc[u] = offp;

    // sequential stream: wave s reads 1 KB contiguous per k-step.
    const uint4* xp = xS + (size_t)bch * RU * 64 + (size_t)(s * C8) * 64 + lane;
    const uint4* aL = buf + s * C8;                            // LDS broadcast
    const uint4* aG = (const uint4*)af + (size_t)(o0 + OT / 2) * RU + s * C8;

#pragma unroll
    for (int c = 0; c < C8; ++c) {
        V4 xv; xv.u = xp[(size_t)c * 64];
#pragma unroll
        for (int u = 0; u < OT / 2; ++u) {          // LDS-path rows
            V4 av; av.u = aL[u * RU + c];
#pragma unroll
            for (int j = 0; j < 4; ++j) {
                const unsigned tv = pk_add(xv.w[j], av.w[j]);
                acc[u] = ISMIN ? pk_min(acc[u], tv) : pk_max(acc[u], tv);
            }
        }
#pragma unroll
        for (int u = 0; u < OT / 2; ++u) {          // scalar-path rows
            V4 av; av.u = aG[(size_t)u * RU + c];
#pragma unroll
            for (int j = 0; j < 4; ++j) {
                const unsigned tv = pk_add(xv.w[j], av.w[j]);
                acc[OT / 2 + u] = ISMIN ? pk_min(acc[OT / 2 + u], tv)
                                        : pk_max(acc[OT / 2 + u], tv);
            }
        }
    }

    __syncthreads();                   // all addend-LDS reads complete
    unsigned short* red = (unsigned short*)buf;     // red[S][OT][64]
#pragma unroll
    for (int u = 0; u < OT; ++u) {
        // fold hi half onto lo (hi lane of shifted word is 0; only lo used)
        const unsigned f = ISMIN ? pk_min(acc[u], acc[u] >> 16)
                                 : pk_max(acc[u], acc[u] >> 16);
        red[(s * OT + u) * 64 + lane] = (unsigned short)(f & 0xffffu);
    }
    __syncthreads();

    if (tid < OT * 64) {               // merge S partials; owner-only write
        const int u = tid >> 6, ln = tid & 63;
        float m = h2f(red[u * 64 + ln]);     // f16->f32 exact
#pragma unroll
        for (int ss = 1; ss < S; ++ss) {
            const float q = h2f(red[(ss * OT + u) * 64 + ln]);
            m = ISMIN ? fminf(m, q) : fmaxf(m, q);
        }
        // value is an f16 value -> f32->f16 reconversion exact
        red[u * 64 + ln] = __half_as_ushort(__float2half(m));
    }
    __syncthreads();

    if (TOUT) {                        // h -> fp16 slab [4][64 oct][64 b]
        if (tid < 64) {
            uint4 w;
            w.x = (unsigned)red[0 * 64 + tid] | ((unsigned)red[1 * 64 + tid] << 16);
            w.y = (unsigned)red[2 * 64 + tid] | ((unsigned)red[3 * 64 + tid] << 16);
            w.z = (unsigned)red[4 * 64 + tid] | ((unsigned)red[5 * 64 + tid] << 16);
            w.w = (unsigned)red[6 * 64 + tid] | ((unsigned)red[7 * 64 + tid] << 16);
            ((uint4*)outp)[(size_t)bch * 4096 + (size_t)(o0 >> 3) * 64 + tid] = w;
        }
    } else {                           // final out[b][o] f32, 64-B chunks
        if (tid < 256) {
            const int bl = tid >> 2, q = tid & 3;
            float4 o4;
            o4.x = h2f(red[(q * 4 + 0) * 64 + bl]);
            o4.y = h2f(red[(q * 4 + 1) * 64 + bl]);
            o4.z = h2f(red[(q * 4 + 2) * 64 + bl]);
            o4.w = h2f(red[(q * 4 + 3) * 64 + bl]);
            ((float4*)outp)[(size_t)(bch * 64 + bl) * 256 + (o0 >> 2) + q] = o4;
        }
    }
}

extern "C" void kernel_launch(void* const* d_in, const int* in_sizes, int n_in,
                              void* d_out, int out_size, void* d_ws, size_t ws_size,
                              hipStream_t stream) {
    const float* x    = (const float*)d_in[0];  // [256,1024] f32
    const int*   sel0 = (const int*)d_in[1];    // [512,1024] i32
    const int*   sel1 = (const int*)d_in[2];    // [1024,512] i32
    float* out = (float*)d_out;                 // [256,1024] f32

    char* ws = (char*)d_ws;
    uint4* xH  = (uint4*)ws;                    // 512 KB: x fp16 slabs
    uint4* hH  = (uint4*)(ws + (512 << 10));    // 256 KB: h fp16 slabs
    uint2* a0f = (uint2*)(ws + (1 << 20));      // 1 MB: layer-0 addends
    uint2* a1f = (uint2*)(ws + (2 << 20));      // 1 MB: layer-1 addends

    // pack: addend expansion (512 blocks) + x transpose (blocks 0..63)
    pack_all<<<512, 256, 0, stream>>>(x, sel0, sel1, xH, a0f, a1f);
    // layer 0: 1024 -> 512, min. OT=8 -> 64 o-octs x 4 bch = 256 blocks.
    daa_layer<1024, 8, true, true><<<256, 1024, 0, stream>>>(
        xH, (const unsigned short*)a0f, hH);
    // layer 1: 512 -> 1024, max. OT=16 -> 64 o-tiles x 4 bch = 256 blocks.
    daa_layer<512, 16, false, false><<<256, 1024, 0, stream>>>(
        hH, (const unsigned short*)a1f, out);
}

// Round 16
// 26.874 us; speedup vs baseline: 151.9972x; 1.0159x over previous
//
#include <hip/hip_runtime.h>
#include <hip/hip_fp16.h>

// DAA autoencoder — 2-dispatch fp16 (R16). Pack kernel eliminated.
//   layer0: h[b][o]   = min_i ( sel0[o][i] ? x[b][i] : 2.0f )
//   layer1: out[b][o] = max_i ( sel1[o][i] ? h[b][i] : -1.0f )
// B=256, IN=1024, HID=512.
//
// R15 lesson: halving bytes+VALU (fp16) changed nothing -> kernels are not
// the cost. History fit: dur ~= F * n_dispatches + ~5us, F ~= 7-10us
// (R12: 5 tiny kernels = 61us; R10/R15: 3 = 25-27us). R16 drops to 2
// dispatches: L0 does its own in-LDS x transpose+f16 convert and inline
// sel->addend expansion; writes h as packed slab hS[bch][oct][b] (uint4).
// L1 streams hS directly (1KB coalesced wave-loads), expands sel1 inline,
// one wave per output row, transposed epilogue via padded LDS.
//
// Accuracy: f32->f16 RN error <= 2.44e-4 on [0,1); min/max are selections
// (no accumulation); +/-inf addends and 2.0/-1.0 exact in f16
// => absmax <= 2.44e-4 < threshold 4.10e-4 (R15 measured 1.22e-4).

#define H_PINF 0x7C00u
#define H_NINF 0xFC00u

__device__ __forceinline__ unsigned pk_add(unsigned a, unsigned b) {
    unsigned r; asm("v_pk_add_f16 %0, %1, %2" : "=v"(r) : "v"(a), "v"(b)); return r;
}
__device__ __forceinline__ unsigned pk_min(unsigned a, unsigned b) {
    unsigned r; asm("v_pk_min_f16 %0, %1, %2" : "=v"(r) : "v"(a), "v"(b)); return r;
}
__device__ __forceinline__ unsigned pk_max(unsigned a, unsigned b) {
    unsigned r; asm("v_pk_max_f16 %0, %1, %2" : "=v"(r) : "v"(a), "v"(b)); return r;
}
__device__ __forceinline__ unsigned hpk(float a, float b) {
    return (unsigned)__half_as_ushort(__float2half(a))
         | ((unsigned)__half_as_ushort(__float2half(b)) << 16);
}
__device__ __forceinline__ float h2f(unsigned short u) {
    __half h = *reinterpret_cast<__half*>(&u);
    return __half2float(h);
}
__device__ __forceinline__ unsigned selpk(int a, int b, unsigned inf) {
    return (a ? 0u : inf) | ((b ? 0u : inf) << 16);
}

// ===== L0: x[256][1024] f32 + sel0 -> hS slabs ===========================
// block = (j = o-oct 0..63) x (bch 0..3); 1024 threads, 16 waves.
// wave s: row r = s>>1 (of 8), i-half = s&1. 8 slices of 128 i.
__global__ __launch_bounds__(1024) void daa_l0(
    const float* __restrict__ x, const int* __restrict__ sel0,
    uint4* __restrict__ hS)           // [4][64][64] uint4 (f16 h slab)
{
    __shared__ unsigned aL[8 * 256];           // 8 rows x 1024 halves (8 KB... x4B=8K words)
    __shared__ uint4 xL[16 * 65];              // slice: 16 ioct x 64 b, pad 65
    __shared__ unsigned short red[16 * 64];    // per-wave partials
    __shared__ unsigned short mrg[8 * 64];     // merged rows

    const int tid  = threadIdx.x;
    const int lane = tid & 63;
    const int s    = __builtin_amdgcn_readfirstlane(tid >> 6);
    const int bch  = blockIdx.x & 3;
    const int j    = blockIdx.x >> 2;          // o-oct: rows 8j..8j+7
    const int b0   = bch * 64;

    // ---- stage sel0 rows 8j..8j+7 as packed f16 addends (wave-uniform use)
    {   // aL layout: [row][128 words of 2 halves]... store as unsigned[8][256]
        // thread tid expands 8 ints -> 4 unsigned (one uint4 slot = 8 halves)
        const int4* sp = (const int4*)sel0;    // [512][256]
        const int row = tid >> 7, ch = tid & 127;   // ch: 8-i chunk
        const int4 v0 = sp[(size_t)(8 * j + row) * 256 + ch * 2 + 0];
        const int4 v1 = sp[(size_t)(8 * j + row) * 256 + ch * 2 + 1];
        unsigned* dst = &aL[row * 256 + ch * 2];    // 2 words... wait 8 halves = 4 words
        // aL as unsigned[8][256]: 256 words = 512 halves?? need 1024 halves ->
        // use [8][512]? Recompute: 1024 halves/row = 512 words. aL[8*512].
        (void)dst;
    }
    // NOTE: correct sized staging below (the block above is superseded).
    __shared__ unsigned aW[8 * 512];           // 8 rows x 512 words (1024 halves)
    {
        const int4* sp = (const int4*)sel0;    // [512 rows][256 int4]
        // 1024 threads x 2 int4 each = 2048 int4 = 8 rows x 256
        const int row = tid >> 7, ch = tid & 127;  // ch indexes pairs of int4
        const int4 v0 = sp[(size_t)(8 * j + row) * 256 + ch * 2 + 0];
        const int4 v1 = sp[(size_t)(8 * j + row) * 256 + ch * 2 + 1];
        unsigned* dst = &aW[row * 512 + ch * 4];
        dst[0] = selpk(v0.x, v0.y, H_PINF);
        dst[1] = selpk(v0.z, v0.w, H_PINF);
        dst[2] = selpk(v1.x, v1.y, H_PINF);
        dst[3] = selpk(v1.z, v1.w, H_PINF);
    }

    unsigned acc = hpk(2.0f, 2.0f);
    const int r    = s >> 1;                   // my output row (0..7)
    const int half = s & 1;                    // my i-half within slice

#pragma unroll 1
    for (int t = 0; t < 8; ++t) {              // 8 slices of 128 i
        __syncthreads();                       // xL free (prev k-loop done)
        {   // stage x[b0..b0+63][t*128 .. +127] -> xL[ioct][b] f16
            const int br = tid >> 4;           // 0..63 batch row
            const int cg = tid & 15;           // 0..15 ioct within slice
            const float* xr = x + (size_t)(b0 + br) * 1024 + t * 128 + cg * 8;
            const float4 f0 = ((const float4*)xr)[0];
            const float4 f1 = ((const float4*)xr)[1];
            uint4 w;
            w.x = hpk(f0.x, f0.y);  w.y = hpk(f0.z, f0.w);
            w.z = hpk(f1.x, f1.y);  w.w = hpk(f1.z, f1.w);
            xL[cg * 65 + br] = w;
        }
        __syncthreads();
        // k-loop: 8 ioct for my half
        const unsigned* ap = &aW[r * 512 + t * 64 + half * 32];
#pragma unroll
        for (int c = 0; c < 8; ++c) {
            const uint4 xv = xL[(half * 8 + c) * 65 + lane];
            const unsigned a0 = ap[c * 4 + 0], a1 = ap[c * 4 + 1];
            const unsigned a2 = ap[c * 4 + 2], a3 = ap[c * 4 + 3];
            acc = pk_min(acc, pk_add(xv.x, a0));
            acc = pk_min(acc, pk_add(xv.y, a1));
            acc = pk_min(acc, pk_add(xv.z, a2));
            acc = pk_min(acc, pk_add(xv.w, a3));
        }
    }

    // fold hi/lo, publish per-wave partial
    {
        const unsigned f = pk_min(acc, acc >> 16);
        red[s * 64 + lane] = (unsigned short)(f & 0xffffu);
    }
    __syncthreads();

    if (tid < 64) {                            // merge halves + pack oct
#pragma unroll
        for (int rr = 0; rr < 8; ++rr) {
            const unsigned short a = red[(2 * rr + 0) * 64 + tid];
            const unsigned short b = red[(2 * rr + 1) * 64 + tid];
            // f16 min via pk_min on lo halves
            const unsigned m = pk_min((unsigned)a, (unsigned)b);
            mrg[rr * 64 + tid] = (unsigned short)(m & 0xffffu);
        }
        uint4 w;
        w.x = (unsigned)mrg[0 * 64 + tid] | ((unsigned)mrg[1 * 64 + tid] << 16);
        w.y = (unsigned)mrg[2 * 64 + tid] | ((unsigned)mrg[3 * 64 + tid] << 16);
        w.z = (unsigned)mrg[4 * 64 + tid] | ((unsigned)mrg[5 * 64 + tid] << 16);
        w.w = (unsigned)mrg[6 * 64 + tid] | ((unsigned)mrg[7 * 64 + tid] << 16);
        hS[(size_t)bch * 4096 + (size_t)j * 64 + tid] = w;   // coalesced 1 KB
    }
}

// ===== L1: hS slabs + sel1 -> out[256][1024] f32 =========================
// block = (j2 = o-16-tile 0..63) x (bch 0..3); 16 waves = 16 output rows.
__global__ __launch_bounds__(1024) void daa_l1(
    const uint4* __restrict__ hS,     // [4][64][64] uint4
    const int* __restrict__ sel1,
    float* __restrict__ out)
{
    __shared__ unsigned aW[16 * 256];          // 16 rows x 512 halves
    __shared__ float redf[16 * 65];            // padded transpose buffer

    const int tid  = threadIdx.x;
    const int lane = tid & 63;
    const int s    = __builtin_amdgcn_readfirstlane(tid >> 6);
    const int bch  = blockIdx.x & 3;
    const int j2   = blockIdx.x >> 2;          // rows 16*j2 .. +15
    const int b0   = bch * 64;

    {   // stage sel1 rows 16j2..16j2+15 as packed addends
        const int4* sp = (const int4*)sel1;    // [1024 rows][128 int4]
        const int row = tid >> 6, ch = tid & 63;
        const int4 v0 = sp[(size_t)(16 * j2 + row) * 128 + ch * 2 + 0];
        const int4 v1 = sp[(size_t)(16 * j2 + row) * 128 + ch * 2 + 1];
        unsigned* dst = &aW[row * 256 + ch * 4];
        dst[0] = selpk(v0.x, v0.y, H_NINF);
        dst[1] = selpk(v0.z, v0.w, H_NINF);
        dst[2] = selpk(v1.x, v1.y, H_NINF);
        dst[3] = selpk(v1.z, v1.w, H_NINF);
    }
    __syncthreads();

    unsigned acc = hpk(-1.0f, -1.0f);
    const uint4* xp = hS + (size_t)bch * 4096 + lane;
    const unsigned* ap = &aW[s * 256];

#pragma unroll 8
    for (int c = 0; c < 64; ++c) {             // 64 octs of hid
        const uint4 xv = xp[c * 64];           // coalesced 1 KB wave-load
        acc = pk_max(acc, pk_add(xv.x, ap[c * 4 + 0]));
        acc = pk_max(acc, pk_add(xv.y, ap[c * 4 + 1]));
        acc = pk_max(acc, pk_add(xv.z, ap[c * 4 + 2]));
        acc = pk_max(acc, pk_add(xv.w, ap[c * 4 + 3]));
    }

    {   // fold hi/lo -> f32, publish row
        const unsigned f = pk_max(acc, acc >> 16);
        redf[s * 65 + lane] = h2f((unsigned short)(f & 0xffffu));
    }
    __syncthreads();

    {   // transposed store: thread (b = tid&63, oo = tid>>6) -> 64-B segs
        const int b = tid & 63, oo = tid >> 6;
        out[(size_t)(b0 + b) * 1024 + 16 * j2 + oo] = redf[oo * 65 + b];
    }
}

extern "C" void kernel_launch(void* const* d_in, const int* in_sizes, int n_in,
                              void* d_out, int out_size, void* d_ws, size_t ws_size,
                              hipStream_t stream) {
    const float* x    = (const float*)d_in[0];  // [256,1024] f32
    const int*   sel0 = (const int*)d_in[1];    // [512,1024] i32
    const int*   sel1 = (const int*)d_in[2];    // [1024,512] i32
    float* out = (float*)d_out;                 // [256,1024] f32

    uint4* hS = (uint4*)d_ws;                   // 256 KB f16 h slabs

    daa_l0<<<256, 1024, 0, stream>>>(x, sel0, hS);
    daa_l1<<<256, 1024, 0, stream>>>(hS, sel1, out);
}